// Round 4
// baseline (338.003 us; speedup 1.0000x reference)
//
#include <hip/hip_runtime.h>
#include <stdint.h>

#define NB 16
#define NPIX 262144            // 512*512
#define K_RANK 104856u         // int(512*512*0.4 - 1)
#define NB1 4096
#define PAD(i) ((i) + ((i) >> 4))

// ---------------- Kernel 1: gray + histogram on bits[31:20] + zero scratch ----------------
__global__ void k_gray_hist(const float* __restrict__ yp, float* __restrict__ gray,
                            unsigned* __restrict__ hist1,
                            unsigned* __restrict__ zr, int zcount) {
    __shared__ unsigned h[NB1];
    const int tid = threadIdx.x;
    const int gtid = blockIdx.x * 256 + tid;
    if (gtid < zcount) zr[gtid] = 0;           // zero hist2/hist3/accum/done for later kernels
    for (int i = tid; i < NB1; i += 256) h[i] = 0;
    __syncthreads();

    const int blk   = blockIdx.x;      // 4096 blocks, 256 per batch
    const int b     = blk >> 8;
    const int chunk = blk & 255;
    const long base = (long)b * 3 * NPIX;
    const int  o    = (chunk * 256 + tid) * 4;

    const float4 c0 = *(const float4*)(yp + base + o);
    const float4 c1 = *(const float4*)(yp + base + NPIX + o);
    const float4 c2 = *(const float4*)(yp + base + 2 * NPIX + o);

    float g0 = (c0.x + c1.x + c2.x) / 3.0f;
    float g1 = (c0.y + c1.y + c2.y) / 3.0f;
    float g2 = (c0.z + c1.z + c2.z) / 3.0f;
    float g3 = (c0.w + c1.w + c2.w) / 3.0f;

    if (gray) {
        *(float4*)(gray + (long)b * NPIX + o) = make_float4(g0, g1, g2, g3);
    }
    atomicAdd(&h[__float_as_uint(g0) >> 20], 1u);
    atomicAdd(&h[__float_as_uint(g1) >> 20], 1u);
    atomicAdd(&h[__float_as_uint(g2) >> 20], 1u);
    atomicAdd(&h[__float_as_uint(g3) >> 20], 1u);
    __syncthreads();

    unsigned* gh = hist1 + b * NB1;
    for (int i = tid; i < NB1; i += 256) {
        unsigned v = h[i];
        if (v) atomicAdd(&gh[i], v);
    }
}

// ---------------- Refine (fused with redundant scan of previous histogram) ----------------
// Every block: scan hist_scan[b] (4096 bins, bank-conflict-free padded LDS) -> digit/prefix,
// then histogram the next digit of prefix-matching gray values into hist_out[b].
__global__ void k_refine(const float* __restrict__ gray, const float* __restrict__ yp,
                         const unsigned* __restrict__ hist_scan,
                         const unsigned* __restrict__ rank_in,
                         const unsigned* __restrict__ prefix_in,
                         int width, int sel_shift, int dig_shift, unsigned dmask,
                         unsigned* __restrict__ hist_out, int nbins_out,
                         unsigned* __restrict__ rank_out, unsigned* __restrict__ prefix_out) {
    __shared__ unsigned sh[NB1 + (NB1 >> 4)];
    __shared__ unsigned wave_sums[4];
    __shared__ unsigned bc_prefix;
    const int tid   = threadIdx.x;
    const int blk   = blockIdx.x;
    const int b     = blk >> 8;
    const int chunk = blk & 255;

    // ---- scan phase ----
    const unsigned* hb = hist_scan + b * NB1;
    for (int i = tid; i < NB1; i += 256) sh[PAD(i)] = hb[i];
    __syncthreads();

    unsigned sum = 0;
    #pragma unroll
    for (int j = 0; j < 16; ++j) sum += sh[tid * 17 + j];
    unsigned inc = sum;
    for (int off = 1; off < 64; off <<= 1) {
        unsigned v = __shfl_up(inc, off);
        if ((tid & 63) >= off) inc += v;
    }
    if ((tid & 63) == 63) wave_sums[tid >> 6] = inc;
    __syncthreads();
    unsigned woff = 0;
    for (int w = 0; w < (tid >> 6); ++w) woff += wave_sums[w];
    const unsigned excl = woff + inc - sum;

    const unsigned r = rank_in ? rank_in[b] : K_RANK;
    const unsigned p = prefix_in ? prefix_in[b] : 0u;
    if (r >= excl && r < excl + sum) {            // exactly one thread
        unsigned cum = excl;
        unsigned d   = (unsigned)(tid * 16);
        #pragma unroll
        for (int j = 0; j < 16; ++j) {
            unsigned c = sh[tid * 17 + j];
            if (cum + c > r) { d = (unsigned)(tid * 16 + j); break; }
            cum += c;
        }
        bc_prefix = (p << width) | d;
        if (chunk == 0) { rank_out[b] = r - cum; prefix_out[b] = bc_prefix; }
    }
    __syncthreads();
    const unsigned pre = bc_prefix;

    // ---- refine phase (reuse sh as output histogram) ----
    for (int i = tid; i < nbins_out; i += 256) sh[i] = 0;
    __syncthreads();

    const int o = (chunk * 256 + tid) * 4;
    float g0, g1, g2, g3;
    if (gray) {
        float4 gv = *(const float4*)(gray + (long)b * NPIX + o);
        g0 = gv.x; g1 = gv.y; g2 = gv.z; g3 = gv.w;
    } else {
        const long base = (long)b * 3 * NPIX;
        float4 c0 = *(const float4*)(yp + base + o);
        float4 c1 = *(const float4*)(yp + base + NPIX + o);
        float4 c2 = *(const float4*)(yp + base + 2 * NPIX + o);
        g0 = (c0.x + c1.x + c2.x) / 3.0f;
        g1 = (c0.y + c1.y + c2.y) / 3.0f;
        g2 = (c0.z + c1.z + c2.z) / 3.0f;
        g3 = (c0.w + c1.w + c2.w) / 3.0f;
    }
    unsigned bits;
    bits = __float_as_uint(g0);
    if ((bits >> sel_shift) == pre) atomicAdd(&sh[(bits >> dig_shift) & dmask], 1u);
    bits = __float_as_uint(g1);
    if ((bits >> sel_shift) == pre) atomicAdd(&sh[(bits >> dig_shift) & dmask], 1u);
    bits = __float_as_uint(g2);
    if ((bits >> sel_shift) == pre) atomicAdd(&sh[(bits >> dig_shift) & dmask], 1u);
    bits = __float_as_uint(g3);
    if ((bits >> sel_shift) == pre) atomicAdd(&sh[(bits >> dig_shift) & dmask], 1u);
    __syncthreads();

    unsigned* gh = hist_out + b * nbins_out;
    for (int i = tid; i < nbins_out; i += 256) {
        unsigned v = sh[i];
        if (v) atomicAdd(&gh[i], v);
    }
}

// ---------------- Loss (fused with scan3 + final reduction) ----------------
__global__ void k_loss(const float* __restrict__ yt, const float* __restrict__ yp,
                       const unsigned* __restrict__ hist3,
                       const unsigned* __restrict__ rank_in,
                       const unsigned* __restrict__ prefix_in,
                       double* __restrict__ accum, unsigned* __restrict__ done,
                       float* __restrict__ out) {
    __shared__ unsigned wave_sums[4];
    __shared__ unsigned bc_thr;
    __shared__ float wsum[4];
    __shared__ int is_last;
    const int tid   = threadIdx.x;
    const int blk   = blockIdx.x;
    const int b     = blk >> 8;
    const int chunk = blk & 255;

    // ---- scan3: 256 bins, one per thread, coalesced global load ----
    const unsigned sum = hist3[b * 256 + tid];
    unsigned inc = sum;
    for (int off = 1; off < 64; off <<= 1) {
        unsigned v = __shfl_up(inc, off);
        if ((tid & 63) >= off) inc += v;
    }
    if ((tid & 63) == 63) wave_sums[tid >> 6] = inc;
    __syncthreads();
    unsigned woff = 0;
    for (int w = 0; w < (tid >> 6); ++w) woff += wave_sums[w];
    const unsigned excl = woff + inc - sum;
    const unsigned r = rank_in[b];
    if (r >= excl && r < excl + sum) {
        bc_thr = (prefix_in[b] << 8) | (unsigned)tid;
    }
    __syncthreads();
    const unsigned thr = bc_thr;

    // ---- loss body ----
    const long base = (long)b * 3 * NPIX;
    const int  o    = (chunk * 256 + tid) * 4;

    float4 p0 = *(const float4*)(yp + base + o);
    float4 p1 = *(const float4*)(yp + base + NPIX + o);
    float4 p2 = *(const float4*)(yp + base + 2 * NPIX + o);
    float4 t0 = *(const float4*)(yt + base + o);
    float4 t1 = *(const float4*)(yt + base + NPIX + o);
    float4 t2 = *(const float4*)(yt + base + 2 * NPIX + o);

    float s = 0.0f;
    {
        float g = (p0.x + p1.x + p2.x) / 3.0f;
        float w = (__float_as_uint(g) <= thr) ? 0.8f : 0.2f;
        s += w * (fabsf(p0.x - t0.x) + fabsf(p1.x - t1.x) + fabsf(p2.x - t2.x));
    }
    {
        float g = (p0.y + p1.y + p2.y) / 3.0f;
        float w = (__float_as_uint(g) <= thr) ? 0.8f : 0.2f;
        s += w * (fabsf(p0.y - t0.y) + fabsf(p1.y - t1.y) + fabsf(p2.y - t2.y));
    }
    {
        float g = (p0.z + p1.z + p2.z) / 3.0f;
        float w = (__float_as_uint(g) <= thr) ? 0.8f : 0.2f;
        s += w * (fabsf(p0.z - t0.z) + fabsf(p1.z - t1.z) + fabsf(p2.z - t2.z));
    }
    {
        float g = (p0.w + p1.w + p2.w) / 3.0f;
        float w = (__float_as_uint(g) <= thr) ? 0.8f : 0.2f;
        s += w * (fabsf(p0.w - t0.w) + fabsf(p1.w - t1.w) + fabsf(p2.w - t2.w));
    }

    for (int off = 32; off > 0; off >>= 1) s += __shfl_down(s, off);
    if ((tid & 63) == 0) wsum[tid >> 6] = s;
    __syncthreads();
    if (tid == 0) {
        float tot = wsum[0] + wsum[1] + wsum[2] + wsum[3];
        atomicAdd(&accum[(blk & 63) * 16], (double)tot);   // 64 cache-line-spread slots
        __threadfence();
        unsigned old = atomicAdd(done, 1u);
        is_last = (old == 4095u) ? 1 : 0;
    }
    __syncthreads();
    if (is_last && tid < 64) {
        double v = atomicAdd(&accum[tid * 16], 0.0);       // atomic read (device-coherent)
        for (int off = 32; off > 0; off >>= 1) v += __shfl_down(v, off);
        if (tid == 0) out[0] = (float)(v / 12582912.0);    // 16*3*512*512
    }
}

extern "C" void kernel_launch(void* const* d_in, const int* in_sizes, int n_in,
                              void* d_out, int out_size, void* d_ws, size_t ws_size,
                              hipStream_t stream) {
    const float* yt = (const float*)d_in[0];   // y_true
    const float* yp = (const float*)d_in[1];   // y_pred
    float* out = (float*)d_out;
    char* ws = (char*)d_ws;

    // ws layout
    unsigned* hist1 = (unsigned*)(ws);               // 262144 B (zeroed by memset)
    unsigned* zr    = (unsigned*)(ws + 262144);      // zero region start
    unsigned* hist2 = (unsigned*)(ws + 262144);      // 262144 B
    unsigned* hist3 = (unsigned*)(ws + 524288);      // 16384 B
    double*   accum = (double*)(ws + 540672);        // 64 slots * 128B = 8192 B
    unsigned* done  = (unsigned*)(ws + 548864);      // 64 B
    unsigned* rank1 = (unsigned*)(ws + 548928);      // 64 B each
    unsigned* pref1 = (unsigned*)(ws + 548992);
    unsigned* rank2 = (unsigned*)(ws + 549056);
    unsigned* pref2 = (unsigned*)(ws + 549120);
    const int zcount = (262144 + 16384 + 8192 + 64) / 4;   // hist2+hist3+accum+done

    float* gray = nullptr;
    const size_t gray_off = 1 << 20;
    if (ws_size >= gray_off + (size_t)NB * NPIX * sizeof(float))
        gray = (float*)(ws + gray_off);

    hipMemsetAsync(hist1, 0, 262144, stream);     // hist1 must be zero before k_gray_hist flush

    k_gray_hist<<<4096, 256, 0, stream>>>(yp, gray, hist1, zr, zcount);
    k_refine<<<4096, 256, 0, stream>>>(gray, yp, hist1, nullptr, nullptr,
                                       12, 20, 8, 0xFFFu, hist2, NB1, rank1, pref1);
    k_refine<<<4096, 256, 0, stream>>>(gray, yp, hist2, rank1, pref1,
                                       12, 8, 0, 0xFFu, hist3, 256, rank2, pref2);
    k_loss<<<4096, 256, 0, stream>>>(yt, yp, hist3, rank2, pref2, accum, done, out);
}

// Round 5
// 169.238 us; speedup vs baseline: 1.9972x; 1.9972x over previous
//
#include <hip/hip_runtime.h>
#include <stdint.h>

#define NB 16
#define NPIX 262144            // 512*512
#define K_RANK 104856u         // int(512*512*0.4 - 1)
#define NB1 4096
#define PAD(i) ((i) + ((i) >> 4))

// ---------------- Kernel 1: gray + histogram on bits[31:20] + zero scratch ----------------
__global__ void k_gray_hist(const float* __restrict__ yp, float* __restrict__ gray,
                            unsigned* __restrict__ hist1,
                            unsigned* __restrict__ zr, int zcount) {
    __shared__ unsigned h[NB1];
    const int tid = threadIdx.x;
    const int gtid = blockIdx.x * 256 + tid;
    if (gtid < zcount) zr[gtid] = 0;           // zero hist2/hist3/accum for later kernels
    for (int i = tid; i < NB1; i += 256) h[i] = 0;
    __syncthreads();

    const int blk   = blockIdx.x;      // 4096 blocks, 256 per batch
    const int b     = blk >> 8;
    const int chunk = blk & 255;
    const long base = (long)b * 3 * NPIX;
    const int  o    = (chunk * 256 + tid) * 4;

    const float4 c0 = *(const float4*)(yp + base + o);
    const float4 c1 = *(const float4*)(yp + base + NPIX + o);
    const float4 c2 = *(const float4*)(yp + base + 2 * NPIX + o);

    float g0 = (c0.x + c1.x + c2.x) / 3.0f;
    float g1 = (c0.y + c1.y + c2.y) / 3.0f;
    float g2 = (c0.z + c1.z + c2.z) / 3.0f;
    float g3 = (c0.w + c1.w + c2.w) / 3.0f;

    if (gray) {
        *(float4*)(gray + (long)b * NPIX + o) = make_float4(g0, g1, g2, g3);
    }
    atomicAdd(&h[__float_as_uint(g0) >> 20], 1u);
    atomicAdd(&h[__float_as_uint(g1) >> 20], 1u);
    atomicAdd(&h[__float_as_uint(g2) >> 20], 1u);
    atomicAdd(&h[__float_as_uint(g3) >> 20], 1u);
    __syncthreads();

    unsigned* gh = hist1 + b * NB1;
    for (int i = tid; i < NB1; i += 256) {
        unsigned v = h[i];
        if (v) atomicAdd(&gh[i], v);
    }
}

// ---------------- Refine (fused with redundant scan of previous histogram) ----------------
__global__ void k_refine(const float* __restrict__ gray, const float* __restrict__ yp,
                         const unsigned* __restrict__ hist_scan,
                         const unsigned* __restrict__ rank_in,
                         const unsigned* __restrict__ prefix_in,
                         int width, int sel_shift, int dig_shift, unsigned dmask,
                         unsigned* __restrict__ hist_out, int nbins_out,
                         unsigned* __restrict__ rank_out, unsigned* __restrict__ prefix_out) {
    __shared__ unsigned sh[NB1 + (NB1 >> 4)];
    __shared__ unsigned wave_sums[4];
    __shared__ unsigned bc_prefix;
    const int tid   = threadIdx.x;
    const int blk   = blockIdx.x;
    const int b     = blk >> 8;
    const int chunk = blk & 255;

    // ---- scan phase ----
    const unsigned* hb = hist_scan + b * NB1;
    for (int i = tid; i < NB1; i += 256) sh[PAD(i)] = hb[i];
    __syncthreads();

    unsigned sum = 0;
    #pragma unroll
    for (int j = 0; j < 16; ++j) sum += sh[tid * 17 + j];
    unsigned inc = sum;
    for (int off = 1; off < 64; off <<= 1) {
        unsigned v = __shfl_up(inc, off);
        if ((tid & 63) >= off) inc += v;
    }
    if ((tid & 63) == 63) wave_sums[tid >> 6] = inc;
    __syncthreads();
    unsigned woff = 0;
    for (int w = 0; w < (tid >> 6); ++w) woff += wave_sums[w];
    const unsigned excl = woff + inc - sum;

    const unsigned r = rank_in ? rank_in[b] : K_RANK;
    const unsigned p = prefix_in ? prefix_in[b] : 0u;
    if (r >= excl && r < excl + sum) {            // exactly one thread
        unsigned cum = excl;
        unsigned d   = (unsigned)(tid * 16);
        #pragma unroll
        for (int j = 0; j < 16; ++j) {
            unsigned c = sh[tid * 17 + j];
            if (cum + c > r) { d = (unsigned)(tid * 16 + j); break; }
            cum += c;
        }
        bc_prefix = (p << width) | d;
        if (chunk == 0) { rank_out[b] = r - cum; prefix_out[b] = bc_prefix; }
    }
    __syncthreads();
    const unsigned pre = bc_prefix;

    // ---- refine phase (reuse sh as output histogram) ----
    for (int i = tid; i < nbins_out; i += 256) sh[i] = 0;
    __syncthreads();

    const int o = (chunk * 256 + tid) * 4;
    float g0, g1, g2, g3;
    if (gray) {
        float4 gv = *(const float4*)(gray + (long)b * NPIX + o);
        g0 = gv.x; g1 = gv.y; g2 = gv.z; g3 = gv.w;
    } else {
        const long base = (long)b * 3 * NPIX;
        float4 c0 = *(const float4*)(yp + base + o);
        float4 c1 = *(const float4*)(yp + base + NPIX + o);
        float4 c2 = *(const float4*)(yp + base + 2 * NPIX + o);
        g0 = (c0.x + c1.x + c2.x) / 3.0f;
        g1 = (c0.y + c1.y + c2.y) / 3.0f;
        g2 = (c0.z + c1.z + c2.z) / 3.0f;
        g3 = (c0.w + c1.w + c2.w) / 3.0f;
    }
    unsigned bits;
    bits = __float_as_uint(g0);
    if ((bits >> sel_shift) == pre) atomicAdd(&sh[(bits >> dig_shift) & dmask], 1u);
    bits = __float_as_uint(g1);
    if ((bits >> sel_shift) == pre) atomicAdd(&sh[(bits >> dig_shift) & dmask], 1u);
    bits = __float_as_uint(g2);
    if ((bits >> sel_shift) == pre) atomicAdd(&sh[(bits >> dig_shift) & dmask], 1u);
    bits = __float_as_uint(g3);
    if ((bits >> sel_shift) == pre) atomicAdd(&sh[(bits >> dig_shift) & dmask], 1u);
    __syncthreads();

    unsigned* gh = hist_out + b * nbins_out;
    for (int i = tid; i < nbins_out; i += 256) {
        unsigned v = sh[i];
        if (v) atomicAdd(&gh[i], v);
    }
}

// ---------------- Loss (fused with scan3; spread f64 atomics, NO fence/done) ----------------
__global__ void k_loss(const float* __restrict__ yt, const float* __restrict__ yp,
                       const unsigned* __restrict__ hist3,
                       const unsigned* __restrict__ rank_in,
                       const unsigned* __restrict__ prefix_in,
                       double* __restrict__ accum) {
    __shared__ unsigned wave_sums[4];
    __shared__ unsigned bc_thr;
    __shared__ float wsum[4];
    const int tid   = threadIdx.x;
    const int blk   = blockIdx.x;
    const int b     = blk >> 8;
    const int chunk = blk & 255;

    // ---- scan3: 256 bins, one per thread, coalesced global load ----
    const unsigned sum = hist3[b * 256 + tid];
    unsigned inc = sum;
    for (int off = 1; off < 64; off <<= 1) {
        unsigned v = __shfl_up(inc, off);
        if ((tid & 63) >= off) inc += v;
    }
    if ((tid & 63) == 63) wave_sums[tid >> 6] = inc;
    __syncthreads();
    unsigned woff = 0;
    for (int w = 0; w < (tid >> 6); ++w) woff += wave_sums[w];
    const unsigned excl = woff + inc - sum;
    const unsigned r = rank_in[b];
    if (r >= excl && r < excl + sum) {
        bc_thr = (prefix_in[b] << 8) | (unsigned)tid;
    }
    __syncthreads();
    const unsigned thr = bc_thr;

    // ---- loss body ----
    const long base = (long)b * 3 * NPIX;
    const int  o    = (chunk * 256 + tid) * 4;

    float4 p0 = *(const float4*)(yp + base + o);
    float4 p1 = *(const float4*)(yp + base + NPIX + o);
    float4 p2 = *(const float4*)(yp + base + 2 * NPIX + o);
    float4 t0 = *(const float4*)(yt + base + o);
    float4 t1 = *(const float4*)(yt + base + NPIX + o);
    float4 t2 = *(const float4*)(yt + base + 2 * NPIX + o);

    float s = 0.0f;
    {
        float g = (p0.x + p1.x + p2.x) / 3.0f;
        float w = (__float_as_uint(g) <= thr) ? 0.8f : 0.2f;
        s += w * (fabsf(p0.x - t0.x) + fabsf(p1.x - t1.x) + fabsf(p2.x - t2.x));
    }
    {
        float g = (p0.y + p1.y + p2.y) / 3.0f;
        float w = (__float_as_uint(g) <= thr) ? 0.8f : 0.2f;
        s += w * (fabsf(p0.y - t0.y) + fabsf(p1.y - t1.y) + fabsf(p2.y - t2.y));
    }
    {
        float g = (p0.z + p1.z + p2.z) / 3.0f;
        float w = (__float_as_uint(g) <= thr) ? 0.8f : 0.2f;
        s += w * (fabsf(p0.z - t0.z) + fabsf(p1.z - t1.z) + fabsf(p2.z - t2.z));
    }
    {
        float g = (p0.w + p1.w + p2.w) / 3.0f;
        float w = (__float_as_uint(g) <= thr) ? 0.8f : 0.2f;
        s += w * (fabsf(p0.w - t0.w) + fabsf(p1.w - t1.w) + fabsf(p2.w - t2.w));
    }

    for (int off = 32; off > 0; off >>= 1) s += __shfl_down(s, off);
    if ((tid & 63) == 0) wsum[tid >> 6] = s;
    __syncthreads();
    if (tid == 0) {
        float tot = wsum[0] + wsum[1] + wsum[2] + wsum[3];
        atomicAdd(&accum[(blk & 63) * 16], (double)tot);   // 64 cache-line-spread slots
    }
}

__global__ void k_final(const double* __restrict__ accum, float* __restrict__ out) {
    const int tid = threadIdx.x;      // 64 threads
    double v = accum[tid * 16];
    for (int off = 32; off > 0; off >>= 1) v += __shfl_down(v, off);
    if (tid == 0) out[0] = (float)(v / 12582912.0);   // 16*3*512*512
}

extern "C" void kernel_launch(void* const* d_in, const int* in_sizes, int n_in,
                              void* d_out, int out_size, void* d_ws, size_t ws_size,
                              hipStream_t stream) {
    const float* yt = (const float*)d_in[0];   // y_true
    const float* yp = (const float*)d_in[1];   // y_pred
    float* out = (float*)d_out;
    char* ws = (char*)d_ws;

    // ws layout
    unsigned* hist1 = (unsigned*)(ws);               // 262144 B (zeroed by memset)
    unsigned* zr    = (unsigned*)(ws + 262144);      // zero region start
    unsigned* hist2 = (unsigned*)(ws + 262144);      // 262144 B
    unsigned* hist3 = (unsigned*)(ws + 524288);      // 16384 B
    double*   accum = (double*)(ws + 540672);        // 64 slots * 128B = 8192 B
    unsigned* rank1 = (unsigned*)(ws + 548928);      // 64 B each
    unsigned* pref1 = (unsigned*)(ws + 548992);
    unsigned* rank2 = (unsigned*)(ws + 549056);
    unsigned* pref2 = (unsigned*)(ws + 549120);
    const int zcount = (262144 + 16384 + 8192) / 4;  // hist2+hist3+accum

    float* gray = nullptr;
    const size_t gray_off = 1 << 20;
    if (ws_size >= gray_off + (size_t)NB * NPIX * sizeof(float))
        gray = (float*)(ws + gray_off);

    hipMemsetAsync(hist1, 0, 262144, stream);     // hist1 must be zero before k_gray_hist flush

    k_gray_hist<<<4096, 256, 0, stream>>>(yp, gray, hist1, zr, zcount);
    k_refine<<<4096, 256, 0, stream>>>(gray, yp, hist1, nullptr, nullptr,
                                       12, 20, 8, 0xFFFu, hist2, NB1, rank1, pref1);
    k_refine<<<4096, 256, 0, stream>>>(gray, yp, hist2, rank1, pref1,
                                       12, 8, 0, 0xFFu, hist3, 256, rank2, pref2);
    k_loss<<<4096, 256, 0, stream>>>(yt, yp, hist3, rank2, pref2, accum);
    k_final<<<1, 64, 0, stream>>>(accum, out);
}